// Round 1
// baseline (3190.006 us; speedup 1.0000x reference)
//
#include <hip/hip_runtime.h>
#include <math.h>

static constexpr int N = 50000;
static constexpr int E = 800000;
static constexpr int F = 128;
static constexpr int H = 64;
static constexpr int G = 512;
static constexpr int C = 10;
static constexpr int CAP = 1024;   // per-graph capacity for score-tied edges (ties ~never happen)

static inline int cdiv(long a, int b) { return (int)((a + b - 1) / b); }

// ---- degree (in-deg over dst), seg = batch[src], edges-per-graph ----
__global__ void k_deg_seg(const int* __restrict__ src, const int* __restrict__ dst,
                          const int* __restrict__ batch, int* __restrict__ deg,
                          int* __restrict__ seg, int* __restrict__ mcnt) {
  int e = blockIdx.x * 256 + threadIdx.x;
  if (e >= E) return;
  atomicAdd(&deg[dst[e]], 1);
  int g = batch[src[e]];
  seg[e] = g;
  atomicAdd(&mcnt[g], 1);
}

__global__ void k_ncnt(const int* __restrict__ batch, int* __restrict__ ncnt) {
  int i = blockIdx.x * 256 + threadIdx.x;
  if (i >= N) return;
  atomicAdd(&ncnt[batch[i]], 1);
}

// ---- layer-1 message scatter: agg[dst] += x[src], 128 floats per edge ----
__global__ void k_scatter1(const float* __restrict__ x, const int* __restrict__ src,
                           const int* __restrict__ dst, float* __restrict__ agg) {
  long t = (long)blockIdx.x * 256 + threadIdx.x;
  if (t >= (long)E * 32) return;
  int e = (int)(t >> 5), q = (int)(t & 31);
  float4 v = ((const float4*)(x + (size_t)src[e] * F))[q];
  float* a = agg + (size_t)dst[e] * F + (size_t)q * 4;
  atomicAdd(a + 0, v.x); atomicAdd(a + 1, v.y);
  atomicAdd(a + 2, v.z); atomicAdd(a + 3, v.w);
}

// ---- weighted scatter for layers 2/3: agg[dst] += ew*h[src], 64 floats ----
__global__ void k_scatter_w(const float* __restrict__ hin, const int* __restrict__ src,
                            const int* __restrict__ dst, const float* __restrict__ ew,
                            float* __restrict__ agg) {
  long t = (long)blockIdx.x * 256 + threadIdx.x;
  if (t >= (long)E * 16) return;
  int e = (int)(t >> 4), q = (int)(t & 15);
  float w = ew[e];
  if (w == 0.0f) return;     // unselected edges contribute exactly 0
  float4 v = ((const float4*)(hin + (size_t)src[e] * H))[q];
  float* a = agg + (size_t)dst[e] * H + (size_t)q * 4;
  atomicAdd(a + 0, v.x * w); atomicAdd(a + 1, v.y * w);
  atomicAdd(a + 2, v.z * w); atomicAdd(a + 3, v.w * w);
}

// ---- fused SAGE linear: out = relu((aggSum/deg) @ Wl + bl + xin @ Wr) ----
// block (64, 8): threadIdx.x = output col h, 8 rows per block
template <int K>
__global__ void k_sage(const float* __restrict__ aggs, const int* __restrict__ deg,
                       const float* __restrict__ xin, const float* __restrict__ Wl,
                       const float* __restrict__ bl, const float* __restrict__ Wr,
                       float* __restrict__ out) {
  int h = threadIdx.x;
  int row = blockIdx.x * 8 + threadIdx.y;
  if (row >= N) return;
  float inv = 1.0f / fmaxf((float)deg[row], 1.0f);
  const float* ar = aggs + (size_t)row * K;
  const float* xr = xin + (size_t)row * K;
  float al = 0.f, rr = 0.f;
#pragma unroll 8
  for (int f = 0; f < K; ++f) {
    al += ar[f] * Wl[f * H + h];
    rr += xr[f] * Wr[f * H + h];
  }
  float v = al * inv + bl[h] + rr;
  out[(size_t)row * H + h] = fmaxf(v, 0.f);
}

// ---- edge scores + order-preserving uint + radix pass-0 histogram ----
__global__ void k_edge_score(const float* __restrict__ h1, const int* __restrict__ src,
                             const int* __restrict__ dst, const int* __restrict__ seg,
                             float* __restrict__ scores, unsigned* __restrict__ scoreu,
                             int* __restrict__ hist) {
  int e = blockIdx.x * 256 + threadIdx.x;
  if (e >= E) return;
  const float4* a = (const float4*)(h1 + (size_t)src[e] * H);
  const float4* b = (const float4*)(h1 + (size_t)dst[e] * H);
  float s = 0.f;
#pragma unroll
  for (int q = 0; q < 16; ++q) {
    float4 u = a[q], v = b[q];
    s += u.x * v.x + u.y * v.y + u.z * v.z + u.w * v.w;
  }
  scores[e] = s;
  unsigned u = __float_as_uint(s);
  u = (u & 0x80000000u) ? ~u : (u | 0x80000000u);   // larger float <=> larger uint
  scoreu[e] = u;
  atomicAdd(&hist[seg[e] * 256 + (int)(u >> 24)], 1);
}

// ---- radix-select histogram for passes 1..3 ----
__global__ void k_hist(const unsigned* __restrict__ scoreu, const int* __restrict__ seg,
                       const unsigned* __restrict__ prefix, int* __restrict__ hist, int pass) {
  int e = blockIdx.x * 256 + threadIdx.x;
  if (e >= E) return;
  unsigned u = scoreu[e];
  int g = seg[e];
  int predshift = 32 - 8 * pass;
  if ((u >> predshift) == (prefix[g] >> predshift))
    atomicAdd(&hist[g * 256 + (int)((u >> (24 - 8 * pass)) & 0xFFu)], 1);
}

// ---- descending bucket scan per graph ----
__global__ void k_scan(const int* __restrict__ hist, const int* __restrict__ mcnt,
                       unsigned* __restrict__ prefix, int* __restrict__ krem, int pass) {
  int g = blockIdx.x * 256 + threadIdx.x;
  if (g >= G) return;
  int k = (pass == 0) ? ((mcnt[g] + 1) >> 1) : krem[g];   // ceil(0.5*m)
  const int* hrow = hist + g * 256;
  int cum = 0, bsel = 255, newk = 0;
  if (k > 0) {
    for (int b = 255; b >= 0; --b) {
      int c = hrow[b];
      if (cum + c >= k) { bsel = b; newk = k - cum; break; }
      cum += c;
    }
  }
  unsigned base = (pass == 0) ? 0u : prefix[g];
  prefix[g] = base | ((unsigned)bsel << (24 - 8 * pass));
  krem[g] = newk;
}

// ---- classify edges vs threshold; collect exact-tie candidates ----
__global__ void k_select(const unsigned* __restrict__ scoreu, const float* __restrict__ scores,
                         const int* __restrict__ seg, const unsigned* __restrict__ thresh,
                         int* __restrict__ eqcnt, int* __restrict__ eqlist,
                         float* __restrict__ sampled, float* __restrict__ ew) {
  int e = blockIdx.x * 256 + threadIdx.x;
  if (e >= E) return;
  unsigned u = scoreu[e];
  int g = seg[e];
  unsigned t = thresh[g];
  float sel = 0.f;
  if (u > t) sel = 1.f;
  else if (u == t) {
    int slot = atomicAdd(&eqcnt[g], 1);
    if (slot < CAP) eqlist[g * CAP + slot] = e;
  }
  sampled[e] = sel;
  ew[e] = scores[e] * sel;
}

// ---- resolve ties: pick r lowest-index edges among score==threshold (stable-sort semantics) ----
__global__ void k_resolve(const int* __restrict__ krem, const int* __restrict__ eqcnt,
                          const int* __restrict__ eqlist, const float* __restrict__ scores,
                          float* __restrict__ sampled, float* __restrict__ ew) {
  int g = blockIdx.x * 256 + threadIdx.x;
  if (g >= G) return;
  int c = eqcnt[g]; if (c > CAP) c = CAP;
  int r = krem[g];  if (r > c) r = c;
  const int* lst = eqlist + g * CAP;
  int last = -1;
  for (int i = 0; i < r; ++i) {           // r is 1 in practice
    int mn = 0x7fffffff;
    for (int j = 0; j < c; ++j) {
      int idx = lst[j];
      if (idx > last && idx < mn) mn = idx;
    }
    if (mn == 0x7fffffff) break;
    sampled[mn] = 1.f;
    ew[mn] = scores[mn];
    last = mn;
  }
}

// ---- mean pool over nodes -> per-graph sums ----
__global__ void k_pool(const float* __restrict__ h3, const int* __restrict__ batch,
                       float* __restrict__ pooled) {
  long t = (long)blockIdx.x * 256 + threadIdx.x;
  if (t >= (long)N * 16) return;
  int n = (int)(t >> 4), q = (int)(t & 15);
  int g = batch[n];
  float4 v = ((const float4*)(h3 + (size_t)n * H))[q];
  float* p = pooled + (size_t)g * H + (size_t)q * 4;
  atomicAdd(p + 0, v.x); atomicAdd(p + 1, v.y);
  atomicAdd(p + 2, v.z); atomicAdd(p + 3, v.w);
}

// ---- MLP head + log_softmax: one block (64 threads) per graph ----
__global__ void k_head(const float* __restrict__ pooled, const int* __restrict__ ncnt,
                       const float* __restrict__ W1, const float* __restrict__ b1,
                       const float* __restrict__ W2, const float* __restrict__ b2,
                       float* __restrict__ outp) {
  int g = blockIdx.x;
  int h = threadIdx.x;   // 0..63
  __shared__ float p[H], z1[H], z2[C], lse;
  float inv = 1.f / fmaxf((float)ncnt[g], 1.f);
  p[h] = pooled[(size_t)g * H + h] * inv;
  __syncthreads();
  float acc = b1[h];
#pragma unroll 8
  for (int f = 0; f < H; ++f) acc += p[f] * W1[f * H + h];
  z1[h] = fmaxf(acc, 0.f);
  __syncthreads();
  if (h < C) {
    float a = b2[h];
#pragma unroll 8
    for (int f = 0; f < H; ++f) a += z1[f] * W2[f * C + h];
    z2[h] = a;
  }
  __syncthreads();
  if (h == 0) {
    float m = z2[0];
    for (int c = 1; c < C; ++c) m = fmaxf(m, z2[c]);
    float s = 0.f;
    for (int c = 0; c < C; ++c) s += expf(z2[c] - m);
    lse = m + logf(s);
  }
  __syncthreads();
  if (h < C) outp[(size_t)g * C + h] = z2[h] - lse;
}

extern "C" void kernel_launch(void* const* d_in, const int* in_sizes, int n_in,
                              void* d_out, int out_size, void* d_ws, size_t ws_size,
                              hipStream_t stream) {
  const float* x     = (const float*)d_in[0];
  const int*   ei    = (const int*)d_in[1];
  const int*   batch = (const int*)d_in[2];
  const float* W1l   = (const float*)d_in[3];
  const float* b1l   = (const float*)d_in[4];
  const float* W1r   = (const float*)d_in[5];
  const float* W2l   = (const float*)d_in[6];
  const float* b2l   = (const float*)d_in[7];
  const float* W2r   = (const float*)d_in[8];
  const float* W3l   = (const float*)d_in[9];
  const float* b3l   = (const float*)d_in[10];
  const float* W3r   = (const float*)d_in[11];
  const float* Wlin1 = (const float*)d_in[12];
  const float* blin1 = (const float*)d_in[13];
  const float* Wlin2 = (const float*)d_in[14];
  const float* blin2 = (const float*)d_in[15];

  const int* srcv = ei;        // edge_index row 0
  const int* dstv = ei + E;    // edge_index row 1

  float* out_ls   = (float*)d_out;       // 512*10 log_softmax
  float* out_samp = out_ls + G * C;      // 800000 sampled mask

  // ---- workspace carve (aligned to 256B) ----
  char* w = (char*)d_ws;
  auto carve = [&](size_t bytes) { void* p = (void*)w; w += (bytes + 255) & ~(size_t)255; return p; };
  float*    agg    = (float*)carve((size_t)N * F * 4);   // reused (first N*H) for layers 2/3
  float*    h1     = (float*)carve((size_t)N * H * 4);
  float*    h2     = (float*)carve((size_t)N * H * 4);
  float*    h3     = (float*)carve((size_t)N * H * 4);
  float*    scores = (float*)carve((size_t)E * 4);
  unsigned* scoreu = (unsigned*)carve((size_t)E * 4);
  int*      seg    = (int*)carve((size_t)E * 4);
  float*    ew     = (float*)carve((size_t)E * 4);
  int*      deg    = (int*)carve((size_t)N * 4);
  int*      mcnt   = (int*)carve((size_t)G * 4);
  int*      ncnt   = (int*)carve((size_t)G * 4);
  int*      eqcnt  = (int*)carve((size_t)G * 4);
  unsigned* prefix = (unsigned*)carve((size_t)G * 4);
  int*      krem   = (int*)carve((size_t)G * 4);
  int*      hist   = (int*)carve((size_t)G * 256 * 4);
  int*      eqlist = (int*)carve((size_t)G * CAP * 4);
  float*    pooled = (float*)carve((size_t)G * H * 4);

  // ---- zero accumulators (ws is poisoned 0xAA before every call) ----
  hipMemsetAsync(agg,    0, (size_t)N * F * 4, stream);
  hipMemsetAsync(deg,    0, (size_t)N * 4, stream);
  hipMemsetAsync(mcnt,   0, (size_t)G * 4, stream);
  hipMemsetAsync(ncnt,   0, (size_t)G * 4, stream);
  hipMemsetAsync(eqcnt,  0, (size_t)G * 4, stream);
  hipMemsetAsync(pooled, 0, (size_t)G * H * 4, stream);

  // ---- counts ----
  k_deg_seg<<<cdiv(E, 256), 256, 0, stream>>>(srcv, dstv, batch, deg, seg, mcnt);
  k_ncnt<<<cdiv(N, 256), 256, 0, stream>>>(batch, ncnt);

  // ---- layer 1 ----
  k_scatter1<<<cdiv((long)E * 32, 256), 256, 0, stream>>>(x, srcv, dstv, agg);
  k_sage<F><<<cdiv(N, 8), dim3(64, 8), 0, stream>>>(agg, deg, x, W1l, b1l, W1r, h1);

  // ---- edge scores + per-graph radix top-k select ----
  hipMemsetAsync(hist, 0, (size_t)G * 256 * 4, stream);
  k_edge_score<<<cdiv(E, 256), 256, 0, stream>>>(h1, srcv, dstv, seg, scores, scoreu, hist);
  k_scan<<<cdiv(G, 256), 256, 0, stream>>>(hist, mcnt, prefix, krem, 0);
  for (int p = 1; p <= 3; ++p) {
    hipMemsetAsync(hist, 0, (size_t)G * 256 * 4, stream);
    k_hist<<<cdiv(E, 256), 256, 0, stream>>>(scoreu, seg, prefix, hist, p);
    k_scan<<<cdiv(G, 256), 256, 0, stream>>>(hist, mcnt, prefix, krem, p);
  }
  k_select<<<cdiv(E, 256), 256, 0, stream>>>(scoreu, scores, seg, prefix, eqcnt, eqlist,
                                             out_samp, ew);
  k_resolve<<<cdiv(G, 256), 256, 0, stream>>>(krem, eqcnt, eqlist, scores, out_samp, ew);

  // ---- layer 2 (weighted) ----
  hipMemsetAsync(agg, 0, (size_t)N * H * 4, stream);
  k_scatter_w<<<cdiv((long)E * 16, 256), 256, 0, stream>>>(h1, srcv, dstv, ew, agg);
  k_sage<H><<<cdiv(N, 8), dim3(64, 8), 0, stream>>>(agg, deg, h1, W2l, b2l, W2r, h2);

  // ---- layer 3 (weighted) ----
  hipMemsetAsync(agg, 0, (size_t)N * H * 4, stream);
  k_scatter_w<<<cdiv((long)E * 16, 256), 256, 0, stream>>>(h2, srcv, dstv, ew, agg);
  k_sage<H><<<cdiv(N, 8), dim3(64, 8), 0, stream>>>(agg, deg, h2, W3l, b3l, W3r, h3);

  // ---- pool + head ----
  k_pool<<<cdiv((long)N * 16, 256), 256, 0, stream>>>(h3, batch, pooled);
  k_head<<<G, 64, 0, stream>>>(pooled, ncnt, Wlin1, blin1, Wlin2, blin2, out_ls);
}

// Round 2
// 1407.749 us; speedup vs baseline: 2.2660x; 2.2660x over previous
//
#include <hip/hip_runtime.h>
#include <math.h>

static constexpr int N = 50000;
static constexpr int E = 800000;
static constexpr int F = 128;
static constexpr int H = 64;
static constexpr int G = 512;
static constexpr int C = 10;
static constexpr int CAP = 256;    // per-graph capacity for score-tied edges (ties ~never happen)

static inline int cdiv(long a, int b) { return (int)((a + b - 1) / b); }

// ---- degree (in-deg over dst), seg = batch[src], edges-per-graph ----
__global__ void k_deg_seg(const int* __restrict__ src, const int* __restrict__ dst,
                          const int* __restrict__ batch, int* __restrict__ deg,
                          int* __restrict__ seg, int* __restrict__ mcnt) {
  int e = blockIdx.x * 256 + threadIdx.x;
  if (e >= E) return;
  atomicAdd(&deg[dst[e]], 1);
  int g = batch[src[e]];
  seg[e] = g;
  atomicAdd(&mcnt[g], 1);
}

__global__ void k_ncnt(const int* __restrict__ batch, int* __restrict__ ncnt) {
  int i = blockIdx.x * 256 + threadIdx.x;
  if (i >= N) return;
  atomicAdd(&ncnt[batch[i]], 1);
}

// ---- single-block exclusive scan (1024 threads, 4 elems/thread/iter) ----
__global__ void k_excl_scan(const int* __restrict__ cnt, int* __restrict__ off, int n) {
  __shared__ int buf[1024];
  __shared__ int carry;
  int tid = threadIdx.x;
  if (tid == 0) carry = 0;
  __syncthreads();
  for (int base = 0; base < n; base += 4096) {
    int idx = base + tid * 4;
    int v0 = (idx + 0 < n) ? cnt[idx + 0] : 0;
    int v1 = (idx + 1 < n) ? cnt[idx + 1] : 0;
    int v2 = (idx + 2 < n) ? cnt[idx + 2] : 0;
    int v3 = (idx + 3 < n) ? cnt[idx + 3] : 0;
    int local = v0 + v1 + v2 + v3;
    buf[tid] = local;
    __syncthreads();
    for (int s = 1; s < 1024; s <<= 1) {
      int t = (tid >= s) ? buf[tid - s] : 0;
      __syncthreads();
      buf[tid] += t;
      __syncthreads();
    }
    int excl = carry + buf[tid] - local;
    if (idx + 0 < n) off[idx + 0] = excl;
    if (idx + 1 < n) off[idx + 1] = excl + v0;
    if (idx + 2 < n) off[idx + 2] = excl + v0 + v1;
    if (idx + 3 < n) off[idx + 3] = excl + v0 + v1 + v2;
    __syncthreads();
    if (tid == 0) carry += buf[1023];
    __syncthreads();
  }
  if (tid == 0) off[n] = carry;
}

__global__ void k_copy_i32(const int* __restrict__ a, int* __restrict__ b, int n) {
  int i = blockIdx.x * 256 + threadIdx.x;
  if (i < n) b[i] = a[i];
}

// ---- counting-sort fill: CSR by dst ----
__global__ void k_fill_csr(const int* __restrict__ src, const int* __restrict__ dst,
                           int* __restrict__ cursor, int* __restrict__ csr_src,
                           int* __restrict__ csr_eid) {
  int e = blockIdx.x * 256 + threadIdx.x;
  if (e >= E) return;
  int slot = atomicAdd(&cursor[dst[e]], 1);
  csr_src[slot] = src[e];
  csr_eid[slot] = e;
}

// ---- layer-1 aggregation: gather. one wave per node, lane covers f and f+64 ----
__global__ void k_gather1(const float* __restrict__ x, const int* __restrict__ csr_src,
                          const int* __restrict__ off, float* __restrict__ agg) {
  int node = blockIdx.x * 4 + threadIdx.y;
  if (node >= N) return;
  int lane = threadIdx.x;  // 0..63
  int s0 = off[node], s1 = off[node + 1];
  float a0 = 0.f, a1 = 0.f;
  int i = s0;
  for (; i + 1 < s1; i += 2) {
    const float* xr0 = x + (size_t)csr_src[i] * F;
    const float* xr1 = x + (size_t)csr_src[i + 1] * F;
    a0 += xr0[lane] + xr1[lane];
    a1 += xr0[lane + 64] + xr1[lane + 64];
  }
  if (i < s1) {
    const float* xr = x + (size_t)csr_src[i] * F;
    a0 += xr[lane];
    a1 += xr[lane + 64];
  }
  agg[(size_t)node * F + lane] = a0;
  agg[(size_t)node * F + 64 + lane] = a1;
}

// ---- weighted aggregation for layers 2/3: gather, wave-uniform skip of w==0 ----
__global__ void k_gather_w(const float* __restrict__ hin, const int* __restrict__ csr_src,
                           const float* __restrict__ ew_csr, const int* __restrict__ off,
                           float* __restrict__ agg) {
  int node = blockIdx.x * 4 + threadIdx.y;
  if (node >= N) return;
  int lane = threadIdx.x;
  int s0 = off[node], s1 = off[node + 1];
  float a = 0.f;
  for (int i = s0; i < s1; ++i) {
    float w = ew_csr[i];          // wave-uniform broadcast
    if (w != 0.f) a += w * hin[(size_t)csr_src[i] * H + lane];
  }
  agg[(size_t)node * H + lane] = a;
}

// ---- permute ew into CSR order ----
__global__ void k_permute_ew(const float* __restrict__ ew, const int* __restrict__ csr_eid,
                             float* __restrict__ ew_csr) {
  int i = blockIdx.x * 256 + threadIdx.x;
  if (i >= E) return;
  ew_csr[i] = ew[csr_eid[i]];
}

// ---- fused SAGE linear: out = relu((aggSum/deg) @ Wl + bl + xin @ Wr) ----
template <int K>
__global__ void k_sage(const float* __restrict__ aggs, const int* __restrict__ deg,
                       const float* __restrict__ xin, const float* __restrict__ Wl,
                       const float* __restrict__ bl, const float* __restrict__ Wr,
                       float* __restrict__ out) {
  int h = threadIdx.x;
  int row = blockIdx.x * 8 + threadIdx.y;
  if (row >= N) return;
  float inv = 1.0f / fmaxf((float)deg[row], 1.0f);
  const float* ar = aggs + (size_t)row * K;
  const float* xr = xin + (size_t)row * K;
  float al = 0.f, rr = 0.f;
#pragma unroll 8
  for (int f = 0; f < K; ++f) {
    al += ar[f] * Wl[f * H + h];
    rr += xr[f] * Wr[f * H + h];
  }
  float v = al * inv + bl[h] + rr;
  out[(size_t)row * H + h] = fmaxf(v, 0.f);
}

// ---- edge scores + order-preserving uint + radix pass-0 histogram ----
__global__ void k_edge_score(const float* __restrict__ h1, const int* __restrict__ src,
                             const int* __restrict__ dst, const int* __restrict__ seg,
                             float* __restrict__ scores, unsigned* __restrict__ scoreu,
                             int* __restrict__ hist) {
  int e = blockIdx.x * 256 + threadIdx.x;
  if (e >= E) return;
  const float4* a = (const float4*)(h1 + (size_t)src[e] * H);
  const float4* b = (const float4*)(h1 + (size_t)dst[e] * H);
  float s = 0.f;
#pragma unroll
  for (int q = 0; q < 16; ++q) {
    float4 u = a[q], v = b[q];
    s += u.x * v.x + u.y * v.y + u.z * v.z + u.w * v.w;
  }
  scores[e] = s;
  unsigned u = __float_as_uint(s);
  u = (u & 0x80000000u) ? ~u : (u | 0x80000000u);   // larger float <=> larger uint
  scoreu[e] = u;
  atomicAdd(&hist[seg[e] * 256 + (int)(u >> 24)], 1);
}

// ---- radix-select histogram for passes 1..3 ----
__global__ void k_hist(const unsigned* __restrict__ scoreu, const int* __restrict__ seg,
                       const unsigned* __restrict__ prefix, int* __restrict__ hist, int pass) {
  int e = blockIdx.x * 256 + threadIdx.x;
  if (e >= E) return;
  unsigned u = scoreu[e];
  int g = seg[e];
  int predshift = 32 - 8 * pass;
  if ((u >> predshift) == (prefix[g] >> predshift))
    atomicAdd(&hist[g * 256 + (int)((u >> (24 - 8 * pass)) & 0xFFu)], 1);
}

// ---- descending bucket scan per graph ----
__global__ void k_scan(const int* __restrict__ hist, const int* __restrict__ mcnt,
                       unsigned* __restrict__ prefix, int* __restrict__ krem, int pass) {
  int g = blockIdx.x * 256 + threadIdx.x;
  if (g >= G) return;
  int k = (pass == 0) ? ((mcnt[g] + 1) >> 1) : krem[g];   // ceil(0.5*m)
  const int* hrow = hist + g * 256;
  int cum = 0, bsel = 255, newk = 0;
  if (k > 0) {
    for (int b = 255; b >= 0; --b) {
      int c = hrow[b];
      if (cum + c >= k) { bsel = b; newk = k - cum; break; }
      cum += c;
    }
  }
  unsigned base = (pass == 0) ? 0u : prefix[g];
  prefix[g] = base | ((unsigned)bsel << (24 - 8 * pass));
  krem[g] = newk;
}

// ---- classify edges vs threshold; collect exact-tie candidates ----
__global__ void k_select(const unsigned* __restrict__ scoreu, const float* __restrict__ scores,
                         const int* __restrict__ seg, const unsigned* __restrict__ thresh,
                         int* __restrict__ eqcnt, int* __restrict__ eqlist,
                         float* __restrict__ sampled, float* __restrict__ ew) {
  int e = blockIdx.x * 256 + threadIdx.x;
  if (e >= E) return;
  unsigned u = scoreu[e];
  int g = seg[e];
  unsigned t = thresh[g];
  float sel = 0.f;
  if (u > t) sel = 1.f;
  else if (u == t) {
    int slot = atomicAdd(&eqcnt[g], 1);
    if (slot < CAP) eqlist[g * CAP + slot] = e;
  }
  sampled[e] = sel;
  ew[e] = scores[e] * sel;
}

// ---- resolve ties: pick r lowest-index edges among score==threshold ----
__global__ void k_resolve(const int* __restrict__ krem, const int* __restrict__ eqcnt,
                          const int* __restrict__ eqlist, const float* __restrict__ scores,
                          float* __restrict__ sampled, float* __restrict__ ew) {
  int g = blockIdx.x * 256 + threadIdx.x;
  if (g >= G) return;
  int c = eqcnt[g]; if (c > CAP) c = CAP;
  int r = krem[g];  if (r > c) r = c;
  const int* lst = eqlist + g * CAP;
  int last = -1;
  for (int i = 0; i < r; ++i) {           // r is 1 in practice
    int mn = 0x7fffffff;
    for (int j = 0; j < c; ++j) {
      int idx = lst[j];
      if (idx > last && idx < mn) mn = idx;
    }
    if (mn == 0x7fffffff) break;
    sampled[mn] = 1.f;
    ew[mn] = scores[mn];
    last = mn;
  }
}

// ---- mean pool: batch is sorted, so nodes per graph are contiguous ----
__global__ void k_pool(const float* __restrict__ h3, const int* __restrict__ goff,
                       float* __restrict__ pooled) {
  int g = blockIdx.x;
  int lane = threadIdx.x;  // 0..63
  int s0 = goff[g], s1 = goff[g + 1];
  float a = 0.f;
  for (int n = s0; n < s1; ++n) a += h3[(size_t)n * H + lane];
  pooled[(size_t)g * H + lane] = a;   // sum; head divides by ncnt
}

// ---- MLP head + log_softmax: one block (64 threads) per graph ----
__global__ void k_head(const float* __restrict__ pooled, const int* __restrict__ ncnt,
                       const float* __restrict__ W1, const float* __restrict__ b1,
                       const float* __restrict__ W2, const float* __restrict__ b2,
                       float* __restrict__ outp) {
  int g = blockIdx.x;
  int h = threadIdx.x;   // 0..63
  __shared__ float p[H], z1[H], z2[C], lse;
  float inv = 1.f / fmaxf((float)ncnt[g], 1.f);
  p[h] = pooled[(size_t)g * H + h] * inv;
  __syncthreads();
  float acc = b1[h];
#pragma unroll 8
  for (int f = 0; f < H; ++f) acc += p[f] * W1[f * H + h];
  z1[h] = fmaxf(acc, 0.f);
  __syncthreads();
  if (h < C) {
    float a = b2[h];
#pragma unroll 8
    for (int f = 0; f < H; ++f) a += z1[f] * W2[f * C + h];
    z2[h] = a;
  }
  __syncthreads();
  if (h == 0) {
    float m = z2[0];
    for (int c = 1; c < C; ++c) m = fmaxf(m, z2[c]);
    float s = 0.f;
    for (int c = 0; c < C; ++c) s += expf(z2[c] - m);
    lse = m + logf(s);
  }
  __syncthreads();
  if (h < C) outp[(size_t)g * C + h] = z2[h] - lse;
}

extern "C" void kernel_launch(void* const* d_in, const int* in_sizes, int n_in,
                              void* d_out, int out_size, void* d_ws, size_t ws_size,
                              hipStream_t stream) {
  const float* x     = (const float*)d_in[0];
  const int*   ei    = (const int*)d_in[1];
  const int*   batch = (const int*)d_in[2];
  const float* W1l   = (const float*)d_in[3];
  const float* b1l   = (const float*)d_in[4];
  const float* W1r   = (const float*)d_in[5];
  const float* W2l   = (const float*)d_in[6];
  const float* b2l   = (const float*)d_in[7];
  const float* W2r   = (const float*)d_in[8];
  const float* W3l   = (const float*)d_in[9];
  const float* b3l   = (const float*)d_in[10];
  const float* W3r   = (const float*)d_in[11];
  const float* Wlin1 = (const float*)d_in[12];
  const float* blin1 = (const float*)d_in[13];
  const float* Wlin2 = (const float*)d_in[14];
  const float* blin2 = (const float*)d_in[15];

  const int* srcv = ei;        // edge_index row 0
  const int* dstv = ei + E;    // edge_index row 1

  float* out_ls   = (float*)d_out;       // 512*10 log_softmax
  float* out_samp = out_ls + G * C;      // 800000 sampled mask

  // ---- workspace carve (aligned to 256B) ----
  char* w = (char*)d_ws;
  auto carve = [&](size_t bytes) { void* p = (void*)w; w += (bytes + 255) & ~(size_t)255; return p; };
  float*    agg     = (float*)carve((size_t)N * F * 4);   // reused (first N*H) for layers 2/3
  float*    h1      = (float*)carve((size_t)N * H * 4);
  float*    h2      = (float*)carve((size_t)N * H * 4);
  float*    h3      = (float*)carve((size_t)N * H * 4);
  float*    scores  = (float*)carve((size_t)E * 4);
  unsigned* scoreu  = (unsigned*)carve((size_t)E * 4);
  int*      seg     = (int*)carve((size_t)E * 4);
  float*    ew      = (float*)carve((size_t)E * 4);
  int*      csr_src = (int*)carve((size_t)E * 4);
  int*      csr_eid = (int*)carve((size_t)E * 4);
  float*    ew_csr  = (float*)carve((size_t)E * 4);
  int*      off     = (int*)carve((size_t)(N + 1) * 4);
  int*      cursor  = (int*)carve((size_t)N * 4);
  int*      goff    = (int*)carve((size_t)(G + 1) * 4);
  int*      deg     = (int*)carve((size_t)N * 4);
  int*      mcnt    = (int*)carve((size_t)G * 4);
  int*      ncnt    = (int*)carve((size_t)G * 4);
  int*      eqcnt   = (int*)carve((size_t)G * 4);
  unsigned* prefix  = (unsigned*)carve((size_t)G * 4);
  int*      krem    = (int*)carve((size_t)G * 4);
  int*      hist    = (int*)carve((size_t)G * 256 * 4);
  int*      eqlist  = (int*)carve((size_t)G * CAP * 4);
  float*    pooled  = (float*)carve((size_t)G * H * 4);

  // ---- zero small accumulators ----
  hipMemsetAsync(deg,   0, (size_t)N * 4, stream);
  hipMemsetAsync(mcnt,  0, (size_t)G * 4, stream);
  hipMemsetAsync(ncnt,  0, (size_t)G * 4, stream);
  hipMemsetAsync(eqcnt, 0, (size_t)G * 4, stream);

  // ---- counts + CSR build ----
  k_deg_seg<<<cdiv(E, 256), 256, 0, stream>>>(srcv, dstv, batch, deg, seg, mcnt);
  k_ncnt<<<cdiv(N, 256), 256, 0, stream>>>(batch, ncnt);
  k_excl_scan<<<1, 1024, 0, stream>>>(deg, off, N);
  k_excl_scan<<<1, 1024, 0, stream>>>(ncnt, goff, G);
  k_copy_i32<<<cdiv(N, 256), 256, 0, stream>>>(off, cursor, N);
  k_fill_csr<<<cdiv(E, 256), 256, 0, stream>>>(srcv, dstv, cursor, csr_src, csr_eid);

  // ---- layer 1 ----
  k_gather1<<<cdiv(N, 4), dim3(64, 4), 0, stream>>>(x, csr_src, off, agg);
  k_sage<F><<<cdiv(N, 8), dim3(64, 8), 0, stream>>>(agg, deg, x, W1l, b1l, W1r, h1);

  // ---- edge scores + per-graph radix top-k select ----
  hipMemsetAsync(hist, 0, (size_t)G * 256 * 4, stream);
  k_edge_score<<<cdiv(E, 256), 256, 0, stream>>>(h1, srcv, dstv, seg, scores, scoreu, hist);
  k_scan<<<cdiv(G, 256), 256, 0, stream>>>(hist, mcnt, prefix, krem, 0);
  for (int p = 1; p <= 3; ++p) {
    hipMemsetAsync(hist, 0, (size_t)G * 256 * 4, stream);
    k_hist<<<cdiv(E, 256), 256, 0, stream>>>(scoreu, seg, prefix, hist, p);
    k_scan<<<cdiv(G, 256), 256, 0, stream>>>(hist, mcnt, prefix, krem, p);
  }
  k_select<<<cdiv(E, 256), 256, 0, stream>>>(scoreu, scores, seg, prefix, eqcnt, eqlist,
                                             out_samp, ew);
  k_resolve<<<cdiv(G, 256), 256, 0, stream>>>(krem, eqcnt, eqlist, scores, out_samp, ew);
  k_permute_ew<<<cdiv(E, 256), 256, 0, stream>>>(ew, csr_eid, ew_csr);

  // ---- layer 2 (weighted) ----
  k_gather_w<<<cdiv(N, 4), dim3(64, 4), 0, stream>>>(h1, csr_src, ew_csr, off, agg);
  k_sage<H><<<cdiv(N, 8), dim3(64, 8), 0, stream>>>(agg, deg, h1, W2l, b2l, W2r, h2);

  // ---- layer 3 (weighted) ----
  k_gather_w<<<cdiv(N, 4), dim3(64, 4), 0, stream>>>(h2, csr_src, ew_csr, off, agg);
  k_sage<H><<<cdiv(N, 8), dim3(64, 8), 0, stream>>>(agg, deg, h2, W3l, b3l, W3r, h3);

  // ---- pool + head ----
  k_pool<<<G, 64, 0, stream>>>(h3, goff, pooled);
  k_head<<<G, 64, 0, stream>>>(pooled, ncnt, Wlin1, blin1, Wlin2, blin2, out_ls);
}

// Round 3
// 876.509 us; speedup vs baseline: 3.6394x; 1.6061x over previous
//
#include <hip/hip_runtime.h>
#include <math.h>

static constexpr int N = 50000;
static constexpr int E = 800000;
static constexpr int F = 128;
static constexpr int H = 64;
static constexpr int G = 512;
static constexpr int C = 10;
static constexpr int CAP = 256;    // per-graph capacity for score-tied edges (full-32-bit ties ~never)

static inline int cdiv(long a, int b) { return (int)((a + b - 1) / b); }

// ---- deg (in-deg over dst) + seg + per-graph edge count via LDS hist ----
// grid-stride, few blocks: mcnt flush is 512 atomics/block (kills the 1562-way
// same-address serialization that cost 269us in R2).
__global__ void k_deg_seg(const int* __restrict__ src, const int* __restrict__ dst,
                          const int* __restrict__ batch, int* __restrict__ deg,
                          int* __restrict__ seg, int* __restrict__ mcnt) {
  __shared__ int h[G];
  for (int i = threadIdx.x; i < G; i += 256) h[i] = 0;
  __syncthreads();
  for (int e = blockIdx.x * 256 + threadIdx.x; e < E; e += gridDim.x * 256) {
    atomicAdd(&deg[dst[e]], 1);          // 50k addrs, fire-and-forget
    int g = batch[src[e]];
    seg[e] = g;
    atomicAdd(&h[g], 1);                 // LDS atomic, low contention
  }
  __syncthreads();
  for (int i = threadIdx.x; i < G; i += 256) {
    int v = h[i];
    if (v) atomicAdd(&mcnt[i], v);
  }
}

// ---- graph offsets by boundary detection on sorted batch (no atomics) ----
__global__ void k_goff(const int* __restrict__ batch, int* __restrict__ goff) {
  int i = blockIdx.x * 256 + threadIdx.x;
  if (i >= N) return;
  int b = batch[i];
  if (i == 0) {
    for (int g = 0; g <= b; ++g) goff[g] = 0;
  } else {
    int p = batch[i - 1];
    for (int g = p + 1; g <= b; ++g) goff[g] = i;
  }
  if (i == N - 1) {
    for (int g = b + 1; g <= G; ++g) goff[g] = N;
  }
}

// ---- single-block exclusive scan, shuffle-based (4 barriers/4096-tile) ----
// writes both off[] and cursor[] (CSR fill cursors)
__global__ void k_excl_scan(const int* __restrict__ cnt, int* __restrict__ off,
                            int* __restrict__ cursor, int n) {
  __shared__ int wsum[16];
  __shared__ int carry;
  int tid = threadIdx.x, lane = tid & 63, wv = tid >> 6;
  if (tid == 0) carry = 0;
  __syncthreads();
  for (int base = 0; base < n; base += 4096) {
    int idx = base + tid * 4;
    int v0 = (idx + 0 < n) ? cnt[idx + 0] : 0;
    int v1 = (idx + 1 < n) ? cnt[idx + 1] : 0;
    int v2 = (idx + 2 < n) ? cnt[idx + 2] : 0;
    int v3 = (idx + 3 < n) ? cnt[idx + 3] : 0;
    int local = v0 + v1 + v2 + v3;
    int inc = local;
    for (int d = 1; d < 64; d <<= 1) {
      int t = __shfl_up(inc, d);
      if (lane >= d) inc += t;
    }
    if (lane == 63) wsum[wv] = inc;
    __syncthreads();
    if (tid < 16) {
      int t = wsum[tid];
      for (int d = 1; d < 16; d <<= 1) {
        int u = __shfl_up(t, d);
        if (tid >= d) t += u;
      }
      wsum[tid] = t;
    }
    __syncthreads();
    int woff = (wv > 0) ? wsum[wv - 1] : 0;
    int excl = carry + woff + inc - local;
    if (idx + 0 < n) { off[idx + 0] = excl;                int e = excl;                cursor[idx + 0] = e; }
    if (idx + 1 < n) { off[idx + 1] = excl + v0;                                        cursor[idx + 1] = excl + v0; }
    if (idx + 2 < n) { off[idx + 2] = excl + v0 + v1;                                   cursor[idx + 2] = excl + v0 + v1; }
    if (idx + 3 < n) { off[idx + 3] = excl + v0 + v1 + v2;                              cursor[idx + 3] = excl + v0 + v1 + v2; }
    int total = wsum[15];
    __syncthreads();
    if (tid == 0) carry += total;
    __syncthreads();
  }
  if (threadIdx.x == 0) off[n] = carry;
}

// ---- counting-sort fill: CSR by dst + inverse map edge->slot ----
__global__ void k_fill_csr(const int* __restrict__ src, const int* __restrict__ dst,
                           int* __restrict__ cursor, int* __restrict__ csr_src,
                           int* __restrict__ einv) {
  int e = blockIdx.x * 256 + threadIdx.x;
  if (e >= E) return;
  int slot = atomicAdd(&cursor[dst[e]], 1);
  csr_src[slot] = src[e];
  einv[e] = slot;
}

// ---- layer 1 fused: gather (CSR) + mean + lin_l + lin_r + relu ----
// one wave per node (lane = output h), 8 nodes/block. N % 8 == 0.
__global__ void k_layer1(const float* __restrict__ x, const int* __restrict__ csr_src,
                         const int* __restrict__ off, const float* __restrict__ Wl,
                         const float* __restrict__ bl, const float* __restrict__ Wr,
                         float* __restrict__ out) {
  int ty = threadIdx.y;
  int node = blockIdx.x * 8 + ty;
  int lane = threadIdx.x;
  __shared__ float sagg[8][F];
  __shared__ float sx[8][F];
  int s0 = off[node], s1 = off[node + 1];
  float a0 = 0.f, a1 = 0.f;
  for (int i = s0; i < s1; ++i) {
    const float* xr = x + (size_t)csr_src[i] * F;   // uniform index -> s_load
    a0 += xr[lane];
    a1 += xr[lane + 64];
  }
  const float* xn = x + (size_t)node * F;
  sagg[ty][lane] = a0; sagg[ty][lane + 64] = a1;
  sx[ty][lane] = xn[lane]; sx[ty][lane + 64] = xn[lane + 64];
  __syncthreads();
  float inv = 1.0f / fmaxf((float)(s1 - s0), 1.0f);
  float al = 0.f, rr = 0.f;
#pragma unroll 8
  for (int f = 0; f < F; ++f) {
    al += sagg[ty][f] * Wl[f * H + lane];   // sagg broadcast (free), Wl coalesced
    rr += sx[ty][f] * Wr[f * H + lane];
  }
  out[(size_t)node * H + lane] = fmaxf(al * inv + bl[lane] + rr, 0.f);
}

// ---- layers 2/3 fused: weighted gather + mean + lin_l + lin_r + relu ----
__global__ void k_layer23(const float* __restrict__ hin, const int* __restrict__ csr_src,
                          const float* __restrict__ ew_csr, const int* __restrict__ off,
                          const float* __restrict__ Wl, const float* __restrict__ bl,
                          const float* __restrict__ Wr, float* __restrict__ out) {
  int ty = threadIdx.y;
  int node = blockIdx.x * 8 + ty;
  int lane = threadIdx.x;
  __shared__ float sagg[8][H];
  __shared__ float sx[8][H];
  int s0 = off[node], s1 = off[node + 1];
  float a = 0.f;
  for (int i = s0; i < s1; ++i) {
    float w = ew_csr[i];                    // wave-uniform
    if (w != 0.f) a += w * hin[(size_t)csr_src[i] * H + lane];
  }
  sagg[ty][lane] = a;
  sx[ty][lane] = hin[(size_t)node * H + lane];
  __syncthreads();
  float inv = 1.0f / fmaxf((float)(s1 - s0), 1.0f);
  float al = 0.f, rr = 0.f;
#pragma unroll 8
  for (int f = 0; f < H; ++f) {
    al += sagg[ty][f] * Wl[f * H + lane];
    rr += sx[ty][f] * Wr[f * H + lane];
  }
  out[(size_t)node * H + lane] = fmaxf(al * inv + bl[lane] + rr, 0.f);
}

// ---- edge scores + order-preserving uint + radix pass-0 histogram ----
__global__ void k_edge_score(const float* __restrict__ h1, const int* __restrict__ src,
                             const int* __restrict__ dst, const int* __restrict__ seg,
                             float* __restrict__ scores, unsigned* __restrict__ scoreu,
                             int* __restrict__ hist) {
  int e = blockIdx.x * 256 + threadIdx.x;
  if (e >= E) return;
  const float4* a = (const float4*)(h1 + (size_t)src[e] * H);
  const float4* b = (const float4*)(h1 + (size_t)dst[e] * H);
  float s = 0.f;
#pragma unroll
  for (int q = 0; q < 16; ++q) {
    float4 u = a[q], v = b[q];
    s += u.x * v.x + u.y * v.y + u.z * v.z + u.w * v.w;
  }
  scores[e] = s;
  unsigned u = __float_as_uint(s);
  u = (u & 0x80000000u) ? ~u : (u | 0x80000000u);   // larger float <=> larger uint
  scoreu[e] = u;
  atomicAdd(&hist[seg[e] * 256 + (int)(u >> 24)], 1);
}

// ---- radix-select histogram for passes 1..3 ----
__global__ void k_hist(const unsigned* __restrict__ scoreu, const int* __restrict__ seg,
                       const unsigned* __restrict__ prefix, int* __restrict__ hist, int pass) {
  int e = blockIdx.x * 256 + threadIdx.x;
  if (e >= E) return;
  unsigned u = scoreu[e];
  int g = seg[e];
  int predshift = 32 - 8 * pass;
  if ((u >> predshift) == (prefix[g] >> predshift))
    atomicAdd(&hist[g * 256 + (int)((u >> (24 - 8 * pass)) & 0xFFu)], 1);
}

// ---- descending bucket select: one wave per graph; re-zeroes hist row ----
__global__ void k_scan(int* __restrict__ hist, const int* __restrict__ mcnt,
                       unsigned* __restrict__ prefix, int* __restrict__ krem, int pass) {
  int g = blockIdx.x;
  int lane = threadIdx.x;   // 0..63
  int k = (pass == 0) ? ((mcnt[g] + 1) >> 1) : krem[g];   // ceil(0.5*m)
  int4* row = (int4*)(hist + (size_t)g * 256);
  int4 v = row[lane];                       // bins 4l .. 4l+3
  int vj[4] = {v.x, v.y, v.z, v.w};
  int s = v.x + v.y + v.z + v.w;
  int inc = s;
  for (int d = 1; d < 64; d <<= 1) {
    int t = __shfl_up(inc, d);
    if (lane >= d) inc += t;
  }
  int T = __shfl(inc, 63);                  // total count
  int excl = inc - s;                       // sum of bins < 4*lane
  int pre[4] = {excl, excl + vj[0], excl + vj[0] + vj[1], excl + vj[0] + vj[1] + vj[2]};
  int bsel_l = -1, newk_l = 0;
  if (k > 0) {
    for (int j = 3; j >= 0; --j) {
      int suf = T - pre[j];                 // count of elems in bins >= 4l+j
      if (suf >= k) { bsel_l = 4 * lane + j; newk_l = k - (suf - vj[j]); break; }
    }
  }
  unsigned long long mask = __ballot(bsel_l >= 0);
  int bsel = 255, newk = 0;
  if (k > 0 && mask) {
    int hi = 63 - __builtin_clzll(mask);
    bsel = __shfl(bsel_l, hi);
    newk = __shfl(newk_l, hi);
  }
  if (lane == 0) {
    unsigned base = (pass == 0) ? 0u : prefix[g];
    prefix[g] = base | ((unsigned)bsel << (24 - 8 * pass));
    krem[g] = newk;
  }
  row[lane] = make_int4(0, 0, 0, 0);        // ready for next pass (replaces memset)
}

// ---- classify edges vs threshold; write sampled + CSR-ordered ew ----
__global__ void k_select(const unsigned* __restrict__ scoreu, const float* __restrict__ scores,
                         const int* __restrict__ seg, const unsigned* __restrict__ thresh,
                         const int* __restrict__ einv, int* __restrict__ eqcnt,
                         int* __restrict__ eqlist, float* __restrict__ sampled,
                         float* __restrict__ ew_csr) {
  int e = blockIdx.x * 256 + threadIdx.x;
  if (e >= E) return;
  unsigned u = scoreu[e];
  int g = seg[e];
  unsigned t = thresh[g];
  float sel = 0.f;
  if (u > t) sel = 1.f;
  else if (u == t) {
    int slot = atomicAdd(&eqcnt[g], 1);
    if (slot < CAP) eqlist[g * CAP + slot] = e;
  }
  sampled[e] = sel;
  ew_csr[einv[e]] = scores[e] * sel;
}

// ---- resolve ties: pick r lowest-index edges among exact-threshold scores ----
__global__ void k_resolve(const int* __restrict__ krem, const int* __restrict__ eqcnt,
                          const int* __restrict__ eqlist, const float* __restrict__ scores,
                          const int* __restrict__ einv, float* __restrict__ sampled,
                          float* __restrict__ ew_csr) {
  int g = blockIdx.x * 256 + threadIdx.x;
  if (g >= G) return;
  int c = eqcnt[g]; if (c > CAP) c = CAP;
  int r = krem[g];  if (r > c) r = c;
  const int* lst = eqlist + g * CAP;
  int last = -1;
  for (int i = 0; i < r; ++i) {           // r is ~1 in practice
    int mn = 0x7fffffff;
    for (int j = 0; j < c; ++j) {
      int idx = lst[j];
      if (idx > last && idx < mn) mn = idx;
    }
    if (mn == 0x7fffffff) break;
    sampled[mn] = 1.f;
    ew_csr[einv[mn]] = scores[mn];
    last = mn;
  }
}

// ---- fused mean-pool + MLP head + log_softmax: one block per graph ----
__global__ void k_poolhead(const float* __restrict__ h3, const int* __restrict__ goff,
                           const float* __restrict__ W1, const float* __restrict__ b1,
                           const float* __restrict__ W2, const float* __restrict__ b2,
                           float* __restrict__ outp) {
  int g = blockIdx.x;
  int h = threadIdx.x;   // 0..63
  int s0 = goff[g], s1 = goff[g + 1];
  float a = 0.f;
  for (int n = s0; n < s1; ++n) a += h3[(size_t)n * H + h];
  float inv = 1.f / fmaxf((float)(s1 - s0), 1.f);
  __shared__ float p[H], z1[H], z2[C];
  __shared__ float lse;
  p[h] = a * inv;
  __syncthreads();
  float acc = b1[h];
#pragma unroll 8
  for (int f = 0; f < H; ++f) acc += p[f] * W1[f * H + h];
  z1[h] = fmaxf(acc, 0.f);
  __syncthreads();
  if (h < C) {
    float a2 = b2[h];
#pragma unroll 8
    for (int f = 0; f < H; ++f) a2 += z1[f] * W2[f * C + h];
    z2[h] = a2;
  }
  __syncthreads();
  if (h == 0) {
    float m = z2[0];
    for (int c = 1; c < C; ++c) m = fmaxf(m, z2[c]);
    float s = 0.f;
    for (int c = 0; c < C; ++c) s += expf(z2[c] - m);
    lse = m + logf(s);
  }
  __syncthreads();
  if (h < C) outp[(size_t)g * C + h] = z2[h] - lse;
}

extern "C" void kernel_launch(void* const* d_in, const int* in_sizes, int n_in,
                              void* d_out, int out_size, void* d_ws, size_t ws_size,
                              hipStream_t stream) {
  const float* x     = (const float*)d_in[0];
  const int*   ei    = (const int*)d_in[1];
  const int*   batch = (const int*)d_in[2];
  const float* W1l   = (const float*)d_in[3];
  const float* b1l   = (const float*)d_in[4];
  const float* W1r   = (const float*)d_in[5];
  const float* W2l   = (const float*)d_in[6];
  const float* b2l   = (const float*)d_in[7];
  const float* W2r   = (const float*)d_in[8];
  const float* W3l   = (const float*)d_in[9];
  const float* b3l   = (const float*)d_in[10];
  const float* W3r   = (const float*)d_in[11];
  const float* Wlin1 = (const float*)d_in[12];
  const float* blin1 = (const float*)d_in[13];
  const float* Wlin2 = (const float*)d_in[14];
  const float* blin2 = (const float*)d_in[15];

  const int* srcv = ei;        // edge_index row 0
  const int* dstv = ei + E;    // edge_index row 1

  float* out_ls   = (float*)d_out;       // 512*10 log_softmax
  float* out_samp = out_ls + G * C;      // 800000 sampled mask

  // ---- workspace carve (256B-aligned); zero-init block first, one memset ----
  char* w = (char*)d_ws;
  auto carve = [&](size_t bytes) { void* p = (void*)w; w += (bytes + 255) & ~(size_t)255; return p; };
  char* zbase   = w;
  int*      deg     = (int*)carve((size_t)N * 4);
  int*      mcnt    = (int*)carve((size_t)G * 4);
  int*      eqcnt   = (int*)carve((size_t)G * 4);
  int*      hist    = (int*)carve((size_t)G * 256 * 4);
  size_t    zbytes  = (size_t)(w - zbase);
  float*    h1      = (float*)carve((size_t)N * H * 4);
  float*    h2      = (float*)carve((size_t)N * H * 4);
  float*    h3      = (float*)carve((size_t)N * H * 4);
  float*    scores  = (float*)carve((size_t)E * 4);
  unsigned* scoreu  = (unsigned*)carve((size_t)E * 4);
  int*      seg     = (int*)carve((size_t)E * 4);
  float*    ew_csr  = (float*)carve((size_t)E * 4);
  int*      csr_src = (int*)carve((size_t)E * 4);
  int*      einv    = (int*)carve((size_t)E * 4);
  int*      off     = (int*)carve((size_t)(N + 1) * 4);
  int*      cursor  = (int*)carve((size_t)N * 4);
  int*      goff    = (int*)carve((size_t)(G + 1) * 4);
  unsigned* prefix  = (unsigned*)carve((size_t)G * 4);
  int*      krem    = (int*)carve((size_t)G * 4);
  int*      eqlist  = (int*)carve((size_t)G * CAP * 4);

  hipMemsetAsync(zbase, 0, zbytes, stream);

  // ---- counts + CSR build ----
  k_deg_seg<<<128, 256, 0, stream>>>(srcv, dstv, batch, deg, seg, mcnt);
  k_goff<<<cdiv(N, 256), 256, 0, stream>>>(batch, goff);
  k_excl_scan<<<1, 1024, 0, stream>>>(deg, off, cursor, N);
  k_fill_csr<<<cdiv(E, 256), 256, 0, stream>>>(srcv, dstv, cursor, csr_src, einv);

  // ---- layer 1 (fused gather + linear) ----
  k_layer1<<<N / 8, dim3(64, 8), 0, stream>>>(x, csr_src, off, W1l, b1l, W1r, h1);

  // ---- edge scores + per-graph radix top-k select ----
  k_edge_score<<<cdiv(E, 256), 256, 0, stream>>>(h1, srcv, dstv, seg, scores, scoreu, hist);
  k_scan<<<G, 64, 0, stream>>>(hist, mcnt, prefix, krem, 0);
  for (int p = 1; p <= 3; ++p) {
    k_hist<<<cdiv(E, 256), 256, 0, stream>>>(scoreu, seg, prefix, hist, p);
    k_scan<<<G, 64, 0, stream>>>(hist, mcnt, prefix, krem, p);
  }
  k_select<<<cdiv(E, 256), 256, 0, stream>>>(scoreu, scores, seg, prefix, einv,
                                             eqcnt, eqlist, out_samp, ew_csr);
  k_resolve<<<cdiv(G, 256), 256, 0, stream>>>(krem, eqcnt, eqlist, scores, einv,
                                              out_samp, ew_csr);

  // ---- layers 2/3 (fused weighted gather + linear) ----
  k_layer23<<<N / 8, dim3(64, 8), 0, stream>>>(h1, csr_src, ew_csr, off, W2l, b2l, W2r, h2);
  k_layer23<<<N / 8, dim3(64, 8), 0, stream>>>(h2, csr_src, ew_csr, off, W3l, b3l, W3r, h3);

  // ---- fused pool + head ----
  k_poolhead<<<G, 64, 0, stream>>>(h3, goff, Wlin1, blin1, Wlin2, blin2, out_ls);
}

// Round 4
// 629.468 us; speedup vs baseline: 5.0678x; 1.3925x over previous
//
#include <hip/hip_runtime.h>
#include <math.h>

static constexpr int N = 50000;
static constexpr int E = 800000;
static constexpr int F = 128;
static constexpr int H = 64;
static constexpr int G = 512;
static constexpr int C = 10;
static constexpr int CAP = 256;    // per-graph capacity for score-tied edges (full-32-bit ties ~never)

static inline int cdiv(long a, int b) { return (int)((a + b - 1) / b); }

// ---- deg (in-deg over dst) + seg + per-graph edge count via LDS hist ----
__global__ void k_deg_seg(const int* __restrict__ src, const int* __restrict__ dst,
                          const int* __restrict__ batch, int* __restrict__ deg,
                          int* __restrict__ seg, int* __restrict__ mcnt) {
  __shared__ int h[G];
  for (int i = threadIdx.x; i < G; i += 256) h[i] = 0;
  __syncthreads();
  for (int e = blockIdx.x * 256 + threadIdx.x; e < E; e += gridDim.x * 256) {
    atomicAdd(&deg[dst[e]], 1);
    int g = batch[src[e]];
    seg[e] = g;
    atomicAdd(&h[g], 1);
  }
  __syncthreads();
  for (int i = threadIdx.x; i < G; i += 256) {
    int v = h[i];
    if (v) atomicAdd(&mcnt[i], v);
  }
}

// ---- graph offsets by boundary detection on sorted batch ----
__global__ void k_goff(const int* __restrict__ batch, int* __restrict__ goff) {
  int i = blockIdx.x * 256 + threadIdx.x;
  if (i >= N) return;
  int b = batch[i];
  if (i == 0) {
    for (int g = 0; g <= b; ++g) goff[g] = 0;
  } else {
    int p = batch[i - 1];
    for (int g = p + 1; g <= b; ++g) goff[g] = i;
  }
  if (i == N - 1) {
    for (int g = b + 1; g <= G; ++g) goff[g] = N;
  }
}

// ---- single-block exclusive scan, shuffle-based; writes off[] and cursor[] ----
__global__ void k_excl_scan(const int* __restrict__ cnt, int* __restrict__ off,
                            int* __restrict__ cursor, int n) {
  __shared__ int wsum[16];
  __shared__ int carry;
  int tid = threadIdx.x, lane = tid & 63, wv = tid >> 6;
  if (tid == 0) carry = 0;
  __syncthreads();
  for (int base = 0; base < n; base += 4096) {
    int idx = base + tid * 4;
    int v0 = (idx + 0 < n) ? cnt[idx + 0] : 0;
    int v1 = (idx + 1 < n) ? cnt[idx + 1] : 0;
    int v2 = (idx + 2 < n) ? cnt[idx + 2] : 0;
    int v3 = (idx + 3 < n) ? cnt[idx + 3] : 0;
    int local = v0 + v1 + v2 + v3;
    int inc = local;
    for (int d = 1; d < 64; d <<= 1) {
      int t = __shfl_up(inc, d);
      if (lane >= d) inc += t;
    }
    if (lane == 63) wsum[wv] = inc;
    __syncthreads();
    if (tid < 16) {
      int t = wsum[tid];
      for (int d = 1; d < 16; d <<= 1) {
        int u = __shfl_up(t, d);
        if (tid >= d) t += u;
      }
      wsum[tid] = t;
    }
    __syncthreads();
    int woff = (wv > 0) ? wsum[wv - 1] : 0;
    int excl = carry + woff + inc - local;
    if (idx + 0 < n) { off[idx + 0] = excl;                cursor[idx + 0] = excl; }
    if (idx + 1 < n) { off[idx + 1] = excl + v0;           cursor[idx + 1] = excl + v0; }
    if (idx + 2 < n) { off[idx + 2] = excl + v0 + v1;      cursor[idx + 2] = excl + v0 + v1; }
    if (idx + 3 < n) { off[idx + 3] = excl + v0 + v1 + v2; cursor[idx + 3] = excl + v0 + v1 + v2; }
    int total = wsum[15];
    __syncthreads();
    if (tid == 0) carry += total;
    __syncthreads();
  }
  if (threadIdx.x == 0) off[n] = carry;
}

// ---- counting-sort fill: CSR by dst + inverse map edge->slot ----
__global__ void k_fill_csr(const int* __restrict__ src, const int* __restrict__ dst,
                           int* __restrict__ cursor, int* __restrict__ csr_src,
                           int* __restrict__ einv) {
  int e = blockIdx.x * 256 + threadIdx.x;
  if (e >= E) return;
  int slot = atomicAdd(&cursor[dst[e]], 1);
  csr_src[slot] = src[e];
  einv[e] = slot;
}

// ---- dense pre-GEMM: y = in@Wl, r = in@Wr + b. block (64,4), 16 rows/block ----
template <int K>
__global__ void k_gemm2(const float* __restrict__ in, const float* __restrict__ Wl,
                        const float* __restrict__ Wr, const float* __restrict__ b,
                        float* __restrict__ y, float* __restrict__ r) {
  __shared__ float sx[16][K];
  int lane = threadIdx.x, ty = threadIdx.y;
  int tid = ty * 64 + lane;
  int row0 = blockIdx.x * 16;
  const float4* gsrc = (const float4*)(in + (size_t)row0 * K);
  float4* sdst = (float4*)(&sx[0][0]);
#pragma unroll
  for (int i = tid; i < 16 * K / 4; i += 256) sdst[i] = gsrc[i];
  __syncthreads();
  float al[4], ar[4];
  float bias = b[lane];
#pragma unroll
  for (int j = 0; j < 4; ++j) { al[j] = 0.f; ar[j] = bias; }
#pragma unroll 4
  for (int f = 0; f < K; ++f) {
    float wl = Wl[f * H + lane];
    float wr = Wr[f * H + lane];
#pragma unroll
    for (int j = 0; j < 4; ++j) {
      float xv = sx[ty * 4 + j][f];
      al[j] += xv * wl;
      ar[j] += xv * wr;
    }
  }
#pragma unroll
  for (int j = 0; j < 4; ++j) {
    int row = row0 + ty * 4 + j;
    y[(size_t)row * H + lane] = al[j];
    r[(size_t)row * H + lane] = ar[j];
  }
}

// ---- layer-1 aggregation (post-projection): h = relu(mean(y[src]) + r) ----
__global__ void k_agg1(const float* __restrict__ y, const float* __restrict__ r,
                       const int* __restrict__ csr_src, const int* __restrict__ off,
                       float* __restrict__ out) {
  int node = blockIdx.x * 8 + threadIdx.y;
  int lane = threadIdx.x;
  int s0 = off[node], s1 = off[node + 1];
  float a = 0.f;
  int i = s0;
  for (; i + 3 < s1; i += 4) {
    int i0 = csr_src[i], i1 = csr_src[i + 1], i2 = csr_src[i + 2], i3 = csr_src[i + 3];
    float v0 = y[(size_t)i0 * H + lane];
    float v1 = y[(size_t)i1 * H + lane];
    float v2 = y[(size_t)i2 * H + lane];
    float v3 = y[(size_t)i3 * H + lane];
    a += v0; a += v1; a += v2; a += v3;
  }
  for (; i < s1; ++i) a += y[(size_t)csr_src[i] * H + lane];
  float inv = 1.f / fmaxf((float)(s1 - s0), 1.f);
  out[(size_t)node * H + lane] = fmaxf(a * inv + r[(size_t)node * H + lane], 0.f);
}

// ---- weighted aggregation (post-projection): h = relu(sum(w*y[src])/deg + r) ----
__global__ void k_agg_w(const float* __restrict__ y, const float* __restrict__ r,
                        const int* __restrict__ csr_src, const float* __restrict__ ew_csr,
                        const int* __restrict__ off, float* __restrict__ out) {
  int node = blockIdx.x * 8 + threadIdx.y;
  int lane = threadIdx.x;
  int s0 = off[node], s1 = off[node + 1];
  float a = 0.f;
  int i = s0;
  for (; i + 1 < s1; i += 2) {
    float w0 = ew_csr[i], w1 = ew_csr[i + 1];
    int i0 = csr_src[i], i1 = csr_src[i + 1];
    if (w0 != 0.f) a += w0 * y[(size_t)i0 * H + lane];
    if (w1 != 0.f) a += w1 * y[(size_t)i1 * H + lane];
  }
  if (i < s1) {
    float w0 = ew_csr[i];
    if (w0 != 0.f) a += w0 * y[(size_t)csr_src[i] * H + lane];
  }
  float inv = 1.f / fmaxf((float)(s1 - s0), 1.f);
  out[(size_t)node * H + lane] = fmaxf(a * inv + r[(size_t)node * H + lane], 0.f);
}

// ---- edge scores: 16 lanes per edge, float4 coalesced rows + shfl reduce ----
__global__ void k_edge_score(const float* __restrict__ h1, const int* __restrict__ src,
                             const int* __restrict__ dst, const int* __restrict__ seg,
                             float* __restrict__ scores, unsigned* __restrict__ scoreu,
                             int* __restrict__ hist) {
  int t = blockIdx.x * 256 + threadIdx.x;
  int e = t >> 4;
  int sl = t & 15;
  if (e >= E) return;
  const float4* a = (const float4*)(h1 + (size_t)src[e] * H);
  const float4* b = (const float4*)(h1 + (size_t)dst[e] * H);
  float4 av = a[sl], bv = b[sl];
  float p = av.x * bv.x + av.y * bv.y + av.z * bv.z + av.w * bv.w;
  p += __shfl_xor(p, 1);
  p += __shfl_xor(p, 2);
  p += __shfl_xor(p, 4);
  p += __shfl_xor(p, 8);
  if (sl == 0) {
    scores[e] = p;
    unsigned u = __float_as_uint(p);
    u = (u & 0x80000000u) ? ~u : (u | 0x80000000u);
    scoreu[e] = u;
    atomicAdd(&hist[seg[e] * 256 + (int)(u >> 24)], 1);
  }
}

// ---- radix-select histogram for passes 1..3 ----
__global__ void k_hist(const unsigned* __restrict__ scoreu, const int* __restrict__ seg,
                       const unsigned* __restrict__ prefix, int* __restrict__ hist, int pass) {
  int e = blockIdx.x * 256 + threadIdx.x;
  if (e >= E) return;
  unsigned u = scoreu[e];
  int g = seg[e];
  int predshift = 32 - 8 * pass;
  if ((u >> predshift) == (prefix[g] >> predshift))
    atomicAdd(&hist[g * 256 + (int)((u >> (24 - 8 * pass)) & 0xFFu)], 1);
}

// ---- descending bucket select: one wave per graph; re-zeroes hist row ----
__global__ void k_scan(int* __restrict__ hist, const int* __restrict__ mcnt,
                       unsigned* __restrict__ prefix, int* __restrict__ krem, int pass) {
  int g = blockIdx.x;
  int lane = threadIdx.x;
  int k = (pass == 0) ? ((mcnt[g] + 1) >> 1) : krem[g];   // ceil(0.5*m)
  int4* row = (int4*)(hist + (size_t)g * 256);
  int4 v = row[lane];
  int vj[4] = {v.x, v.y, v.z, v.w};
  int s = v.x + v.y + v.z + v.w;
  int inc = s;
  for (int d = 1; d < 64; d <<= 1) {
    int t = __shfl_up(inc, d);
    if (lane >= d) inc += t;
  }
  int T = __shfl(inc, 63);
  int excl = inc - s;
  int pre[4] = {excl, excl + vj[0], excl + vj[0] + vj[1], excl + vj[0] + vj[1] + vj[2]};
  int bsel_l = -1, newk_l = 0;
  if (k > 0) {
    for (int j = 3; j >= 0; --j) {
      int suf = T - pre[j];
      if (suf >= k) { bsel_l = 4 * lane + j; newk_l = k - (suf - vj[j]); break; }
    }
  }
  unsigned long long mask = __ballot(bsel_l >= 0);
  int bsel = 255, newk = 0;
  if (k > 0 && mask) {
    int hi = 63 - __builtin_clzll(mask);
    bsel = __shfl(bsel_l, hi);
    newk = __shfl(newk_l, hi);
  }
  if (lane == 0) {
    unsigned base = (pass == 0) ? 0u : prefix[g];
    prefix[g] = base | ((unsigned)bsel << (24 - 8 * pass));
    krem[g] = newk;
  }
  row[lane] = make_int4(0, 0, 0, 0);
}

// ---- classify edges vs threshold; write sampled + CSR-ordered ew ----
__global__ void k_select(const unsigned* __restrict__ scoreu, const float* __restrict__ scores,
                         const int* __restrict__ seg, const unsigned* __restrict__ thresh,
                         const int* __restrict__ einv, int* __restrict__ eqcnt,
                         int* __restrict__ eqlist, float* __restrict__ sampled,
                         float* __restrict__ ew_csr) {
  int e = blockIdx.x * 256 + threadIdx.x;
  if (e >= E) return;
  unsigned u = scoreu[e];
  int g = seg[e];
  unsigned t = thresh[g];
  float sel = 0.f;
  if (u > t) sel = 1.f;
  else if (u == t) {
    int slot = atomicAdd(&eqcnt[g], 1);
    if (slot < CAP) eqlist[g * CAP + slot] = e;
  }
  sampled[e] = sel;
  ew_csr[einv[e]] = scores[e] * sel;
}

// ---- resolve ties: pick r lowest-index edges among exact-threshold scores ----
__global__ void k_resolve(const int* __restrict__ krem, const int* __restrict__ eqcnt,
                          const int* __restrict__ eqlist, const float* __restrict__ scores,
                          const int* __restrict__ einv, float* __restrict__ sampled,
                          float* __restrict__ ew_csr) {
  int g = blockIdx.x * 256 + threadIdx.x;
  if (g >= G) return;
  int c = eqcnt[g]; if (c > CAP) c = CAP;
  int r = krem[g];  if (r > c) r = c;
  const int* lst = eqlist + g * CAP;
  int last = -1;
  for (int i = 0; i < r; ++i) {
    int mn = 0x7fffffff;
    for (int j = 0; j < c; ++j) {
      int idx = lst[j];
      if (idx > last && idx < mn) mn = idx;
    }
    if (mn == 0x7fffffff) break;
    sampled[mn] = 1.f;
    ew_csr[einv[mn]] = scores[mn];
    last = mn;
  }
}

// ---- fused mean-pool + MLP head + log_softmax: one block per graph ----
__global__ void k_poolhead(const float* __restrict__ h3, const int* __restrict__ goff,
                           const float* __restrict__ W1, const float* __restrict__ b1,
                           const float* __restrict__ W2, const float* __restrict__ b2,
                           float* __restrict__ outp) {
  int g = blockIdx.x;
  int h = threadIdx.x;
  int s0 = goff[g], s1 = goff[g + 1];
  float a = 0.f;
  for (int n = s0; n < s1; ++n) a += h3[(size_t)n * H + h];
  float inv = 1.f / fmaxf((float)(s1 - s0), 1.f);
  __shared__ float p[H], z1[H], z2[C];
  __shared__ float lse;
  p[h] = a * inv;
  __syncthreads();
  float acc = b1[h];
#pragma unroll 8
  for (int f = 0; f < H; ++f) acc += p[f] * W1[f * H + h];
  z1[h] = fmaxf(acc, 0.f);
  __syncthreads();
  if (h < C) {
    float a2 = b2[h];
#pragma unroll 8
    for (int f = 0; f < H; ++f) a2 += z1[f] * W2[f * C + h];
    z2[h] = a2;
  }
  __syncthreads();
  if (h == 0) {
    float m = z2[0];
    for (int c = 1; c < C; ++c) m = fmaxf(m, z2[c]);
    float s = 0.f;
    for (int c = 0; c < C; ++c) s += expf(z2[c] - m);
    lse = m + logf(s);
  }
  __syncthreads();
  if (h < C) outp[(size_t)g * C + h] = z2[h] - lse;
}

extern "C" void kernel_launch(void* const* d_in, const int* in_sizes, int n_in,
                              void* d_out, int out_size, void* d_ws, size_t ws_size,
                              hipStream_t stream) {
  const float* x     = (const float*)d_in[0];
  const int*   ei    = (const int*)d_in[1];
  const int*   batch = (const int*)d_in[2];
  const float* W1l   = (const float*)d_in[3];
  const float* b1l   = (const float*)d_in[4];
  const float* W1r   = (const float*)d_in[5];
  const float* W2l   = (const float*)d_in[6];
  const float* b2l   = (const float*)d_in[7];
  const float* W2r   = (const float*)d_in[8];
  const float* W3l   = (const float*)d_in[9];
  const float* b3l   = (const float*)d_in[10];
  const float* W3r   = (const float*)d_in[11];
  const float* Wlin1 = (const float*)d_in[12];
  const float* blin1 = (const float*)d_in[13];
  const float* Wlin2 = (const float*)d_in[14];
  const float* blin2 = (const float*)d_in[15];

  const int* srcv = ei;        // edge_index row 0
  const int* dstv = ei + E;    // edge_index row 1

  float* out_ls   = (float*)d_out;       // 512*10 log_softmax
  float* out_samp = out_ls + G * C;      // 800000 sampled mask

  // ---- workspace carve (256B-aligned); zero-init block first, one memset ----
  char* w = (char*)d_ws;
  auto carve = [&](size_t bytes) { void* p = (void*)w; w += (bytes + 255) & ~(size_t)255; return p; };
  char* zbase   = w;
  int*      deg     = (int*)carve((size_t)N * 4);
  int*      mcnt    = (int*)carve((size_t)G * 4);
  int*      eqcnt   = (int*)carve((size_t)G * 4);
  int*      hist    = (int*)carve((size_t)G * 256 * 4);
  size_t    zbytes  = (size_t)(w - zbase);
  float*    h1      = (float*)carve((size_t)N * H * 4);
  float*    h2      = (float*)carve((size_t)N * H * 4);
  float*    h3      = (float*)carve((size_t)N * H * 4);
  float*    yb      = (float*)carve((size_t)N * H * 4);   // projected-left buffer
  float*    rb      = (float*)carve((size_t)N * H * 4);   // projected-right buffer
  float*    scores  = (float*)carve((size_t)E * 4);
  unsigned* scoreu  = (unsigned*)carve((size_t)E * 4);
  int*      seg     = (int*)carve((size_t)E * 4);
  float*    ew_csr  = (float*)carve((size_t)E * 4);
  int*      csr_src = (int*)carve((size_t)E * 4);
  int*      einv    = (int*)carve((size_t)E * 4);
  int*      off     = (int*)carve((size_t)(N + 1) * 4);
  int*      cursor  = (int*)carve((size_t)N * 4);
  int*      goff    = (int*)carve((size_t)(G + 1) * 4);
  unsigned* prefix  = (unsigned*)carve((size_t)G * 4);
  int*      krem    = (int*)carve((size_t)G * 4);
  int*      eqlist  = (int*)carve((size_t)G * CAP * 4);

  hipMemsetAsync(zbase, 0, zbytes, stream);

  // ---- counts + CSR build ----
  k_deg_seg<<<128, 256, 0, stream>>>(srcv, dstv, batch, deg, seg, mcnt);
  k_goff<<<cdiv(N, 256), 256, 0, stream>>>(batch, goff);
  k_excl_scan<<<1, 1024, 0, stream>>>(deg, off, cursor, N);
  k_fill_csr<<<cdiv(E, 256), 256, 0, stream>>>(srcv, dstv, cursor, csr_src, einv);

  // ---- layer 1: dense projections then light gather ----
  k_gemm2<F><<<N / 16, dim3(64, 4), 0, stream>>>(x, W1l, W1r, b1l, yb, rb);
  k_agg1<<<N / 8, dim3(64, 8), 0, stream>>>(yb, rb, csr_src, off, h1);

  // ---- edge scores + per-graph radix top-k select ----
  k_edge_score<<<cdiv((long)E * 16, 256), 256, 0, stream>>>(h1, srcv, dstv, seg,
                                                            scores, scoreu, hist);
  k_scan<<<G, 64, 0, stream>>>(hist, mcnt, prefix, krem, 0);
  for (int p = 1; p <= 3; ++p) {
    k_hist<<<cdiv(E, 256), 256, 0, stream>>>(scoreu, seg, prefix, hist, p);
    k_scan<<<G, 64, 0, stream>>>(hist, mcnt, prefix, krem, p);
  }
  k_select<<<cdiv(E, 256), 256, 0, stream>>>(scoreu, scores, seg, prefix, einv,
                                             eqcnt, eqlist, out_samp, ew_csr);
  k_resolve<<<cdiv(G, 256), 256, 0, stream>>>(krem, eqcnt, eqlist, scores, einv,
                                              out_samp, ew_csr);

  // ---- layer 2: projections + weighted gather ----
  k_gemm2<H><<<N / 16, dim3(64, 4), 0, stream>>>(h1, W2l, W2r, b2l, yb, rb);
  k_agg_w<<<N / 8, dim3(64, 8), 0, stream>>>(yb, rb, csr_src, ew_csr, off, h2);

  // ---- layer 3 ----
  k_gemm2<H><<<N / 16, dim3(64, 4), 0, stream>>>(h2, W3l, W3r, b3l, yb, rb);
  k_agg_w<<<N / 8, dim3(64, 8), 0, stream>>>(yb, rb, csr_src, ew_csr, off, h3);

  // ---- fused pool + head ----
  k_poolhead<<<G, 64, 0, stream>>>(h3, goff, Wlin1, blin1, Wlin2, blin2, out_ls);
}